// Round 5
// baseline (1047.246 us; speedup 1.0000x reference)
//
#include <hip/hip_runtime.h>
#include <math.h>

// Vanilla RNN: h_t = tanh(h_{t-1} @ wh + x_t @ wx + b), out = h_T  [B,1,H]
// B=256, T=2048, H=256, fp32 in/out.
//
// Round 4 = round 3 + dependency-latency fixes in the scan:
//  - k-split=2: per col-tile, two INDEPENDENT 4-deep MFMA chains instead of
//    one 8-deep chain (MFMA dependent latency ~64cy was the dominant serial
//    cost: 512cy/step). Only reg0 of each acc is read; combine is 6 cndmask
//    + 1 add.
//  - xw-seed prefetch: xwc4[ps] for chunk c is fully written during chunk
//    c-1 (barrier-protected), so step ts+1's seed is loaded during step ts's
//    MFMA phase -> its LDS latency leaves the critical path.
//  - Everything else (wave specialization, replicated-row MFMA recurrence,
//    paced GEMM role, 1 raw s_barrier/step) unchanged from round 3.

typedef _Float16 f16;
typedef _Float16 f16x4 __attribute__((ext_vector_type(4)));
typedef _Float16 f16x8 __attribute__((ext_vector_type(8)));
typedef float    f32x4 __attribute__((ext_vector_type(4)));

#define Bv 256
#define Tv 2048
#define Hv 256
#define TC 32
#define NCHUNK (Tv/TC)
#define XS_LD 264          // f16 row stride (528B -> 2-way banks, free)
#define XW_TS (TC+1)       // ts-dim pad: cq stride 33*16B=528B -> 2-way banks

#define LGKM_BARRIER() do { \
    asm volatile("s_waitcnt lgkmcnt(0)" ::: "memory"); \
    __builtin_amdgcn_s_barrier(); \
} while (0)

#define MFMA16(a, b, c) __builtin_amdgcn_mfma_f32_16x16x32_f16((a), (b), (c), 0, 0, 0)

__device__ __forceinline__ f16x4 cvt4(float4 v) {
    f16x4 r; r[0] = (f16)v.x; r[1] = (f16)v.y; r[2] = (f16)v.z; r[3] = (f16)v.w;
    return r;
}

__global__ __launch_bounds__(512, 1)
void HiddenLayer_704374636647_kernel(const float* __restrict__ x,
                                     const float* __restrict__ wx,
                                     const float* __restrict__ wh,
                                     const float* __restrict__ bias,
                                     float* __restrict__ out)
{
    __shared__ __align__(16) f16   xs16[TC][XS_LD];        // 16.9 KB
    __shared__ __align__(16) float xwc4[2][64][XW_TS][4];  // 67.6 KB
    __shared__ __align__(16) f16   hbuf[2][Hv];            //  1.0 KB

    const int  tid   = threadIdx.x;
    const int  wave  = tid >> 6;
    const int  lane  = tid & 63;
    const int  b     = blockIdx.x;
    const bool sw    = (wave < 4);            // scan role
    const int  sg    = sw ? wave : wave - 4;  // role-group 0..3
    const int  wbase = sg * 64;               // 64-col slice owned by group
    const int  l15   = lane & 15;
    const int  grp   = lane >> 4;             // 0..3
    const int  cq    = sg * 16 + l15;         // xwc4 column-quad index
    const int  koff  = grp * 8;               // A-frag k-offset

    const float* xb = x + (size_t)b * Tv * Hv;

    // ---- GEMM waves: global x prefetch registers (8 rows x 4 f32/lane)
    float4 xr0, xr1, xr2, xr3, xr4, xr5, xr6, xr7;
#define LOADX(cc) do { const float* p_ = xb + ((size_t)(cc) * TC + sg * 8) * Hv + lane * 4; \
    xr0 = *(const float4*)(p_);          xr1 = *(const float4*)(p_ +     Hv); \
    xr2 = *(const float4*)(p_ + 2 * Hv); xr3 = *(const float4*)(p_ + 3 * Hv); \
    xr4 = *(const float4*)(p_ + 4 * Hv); xr5 = *(const float4*)(p_ + 5 * Hv); \
    xr6 = *(const float4*)(p_ + 6 * Hv); xr7 = *(const float4*)(p_ + 7 * Hv); } while (0)

    if (!sw) LOADX(0);

    // ---- weight B-frags (identical layout for both roles, different matrix):
    //      tile t covers cols wbase + t*16 + l15; k = kt*32 + grp*8 + e
    const float* wsrc = sw ? wh : wx;
    f16x8 wf[4][8];
    #pragma unroll
    for (int t = 0; t < 4; ++t) {
        #pragma unroll
        for (int kt = 0; kt < 8; ++kt) {
            const float* p = wsrc + (size_t)(kt * 32 + koff) * Hv + wbase + t * 16 + l15;
            f16x8 v;
            #pragma unroll
            for (int e = 0; e < 8; ++e) v[e] = (f16)p[(size_t)e * Hv];
            wf[t][kt] = v;
        }
    }

    float bc0 = 0.f, bc1 = 0.f, bc2 = 0.f, bc3 = 0.f;
    if (!sw) {
        bc0 = bias[wbase + l15];      bc1 = bias[wbase + 16 + l15];
        bc2 = bias[wbase + 32 + l15]; bc3 = bias[wbase + 48 + l15];
    }

    if (sw) hbuf[0][tid] = (f16)0.0f;   // h_0 = 0 (tid 0..255 == scan lanes)

    int   cur     = 0;
    float th_keep = 0.0f;

    #pragma unroll 1
    for (int phase = 0; phase <= NCHUNK; ++phase) {
        if (sw) {
            // ================= SCAN ROLE =================
            if (phase == 0) {
                for (int i = 0; i < TC; ++i) LGKM_BARRIER();
            } else {
                const int ps = (phase - 1) & 1;
                // xwc4[ps] was fully written during the previous phase ->
                // all 32 seeds are readable at any point in this chunk.
                f32x4 xwn = *(const f32x4*)&xwc4[ps][cq][0][0];
                for (int ts = 0; ts < TC; ++ts) {
                    const f32x4 xw = xwn;
                    const f16*  hp = &hbuf[cur][koff];
                    // issue all h-frag reads, then next seed's read (its
                    // latency hides under the MFMA chains)
                    f16x8 ha0 = *(const f16x8*)(hp);
                    f16x8 ha1 = *(const f16x8*)(hp + 32);
                    f16x8 ha2 = *(const f16x8*)(hp + 64);
                    f16x8 ha3 = *(const f16x8*)(hp + 96);
                    f16x8 ha4 = *(const f16x8*)(hp + 128);
                    f16x8 ha5 = *(const f16x8*)(hp + 160);
                    f16x8 ha6 = *(const f16x8*)(hp + 192);
                    f16x8 ha7 = *(const f16x8*)(hp + 224);
                    const int tsn = (ts + 1 < TC) ? ts + 1 : ts;
                    xwn = *(const f32x4*)&xwc4[ps][cq][tsn][0];

                    // k-split=2: two independent 4-deep chains per tile.
                    // Split0 seeded with xw (C row-seed only matters in reg0).
                    f32x4 a0A = {xw[0], 0.f, 0.f, 0.f}, a0B = {0.f, 0.f, 0.f, 0.f};
                    f32x4 a1A = {xw[1], 0.f, 0.f, 0.f}, a1B = {0.f, 0.f, 0.f, 0.f};
                    f32x4 a2A = {xw[2], 0.f, 0.f, 0.f}, a2B = {0.f, 0.f, 0.f, 0.f};
                    f32x4 a3A = {xw[3], 0.f, 0.f, 0.f}, a3B = {0.f, 0.f, 0.f, 0.f};

                    a0A = MFMA16(ha0, wf[0][0], a0A);  a0B = MFMA16(ha4, wf[0][4], a0B);
                    a1A = MFMA16(ha0, wf[1][0], a1A);  a1B = MFMA16(ha4, wf[1][4], a1B);
                    a2A = MFMA16(ha0, wf[2][0], a2A);  a2B = MFMA16(ha4, wf[2][4], a2B);
                    a3A = MFMA16(ha0, wf[3][0], a3A);  a3B = MFMA16(ha4, wf[3][4], a3B);

                    a0A = MFMA16(ha1, wf[0][1], a0A);  a0B = MFMA16(ha5, wf[0][5], a0B);
                    a1A = MFMA16(ha1, wf[1][1], a1A);  a1B = MFMA16(ha5, wf[1][5], a1B);
                    a2A = MFMA16(ha1, wf[2][1], a2A);  a2B = MFMA16(ha5, wf[2][5], a2B);
                    a3A = MFMA16(ha1, wf[3][1], a3A);  a3B = MFMA16(ha5, wf[3][5], a3B);

                    a0A = MFMA16(ha2, wf[0][2], a0A);  a0B = MFMA16(ha6, wf[0][6], a0B);
                    a1A = MFMA16(ha2, wf[1][2], a1A);  a1B = MFMA16(ha6, wf[1][6], a1B);
                    a2A = MFMA16(ha2, wf[2][2], a2A);  a2B = MFMA16(ha6, wf[2][6], a2B);
                    a3A = MFMA16(ha2, wf[3][2], a3A);  a3B = MFMA16(ha6, wf[3][6], a3B);

                    a0A = MFMA16(ha3, wf[0][3], a0A);  a0B = MFMA16(ha7, wf[0][7], a0B);
                    a1A = MFMA16(ha3, wf[1][3], a1A);  a1B = MFMA16(ha7, wf[1][7], a1B);
                    a2A = MFMA16(ha3, wf[2][3], a2A);  a2B = MFMA16(ha7, wf[2][7], a2B);
                    a3A = MFMA16(ha3, wf[3][3], a3A);  a3B = MFMA16(ha7, wf[3][7], a3B);

                    // this lane owns tile (grp): col = wbase + grp*16 + l15
                    float sA01 = (grp & 1) ? a1A[0] : a0A[0];
                    float sA23 = (grp & 1) ? a3A[0] : a2A[0];
                    float sA   = (grp & 2) ? sA23 : sA01;
                    float sB01 = (grp & 1) ? a1B[0] : a0B[0];
                    float sB23 = (grp & 1) ? a3B[0] : a2B[0];
                    float sB   = (grp & 2) ? sB23 : sB01;
                    float s    = sA + sB;

                    float scv = fminf(fmaxf(s, -12.f), 12.f);
                    float e   = __expf(2.f * scv);
                    float th  = __fdividef(e - 1.f, e + 1.f);
                    th_keep = th;
                    hbuf[cur ^ 1][wbase + lane] = (f16)th;
                    LGKM_BARRIER();
                    cur ^= 1;
                }
            }
        } else {
            // ================= GEMM ROLE (produces chunk `phase`) =================
            if (phase < NCHUNK) {
                {   // slice 0: stage rows sg*8+0..3 (f32->f16)
                    f16* r = &xs16[sg * 8][lane * 4];
                    *(f16x4*)(r)            = cvt4(xr0);
                    *(f16x4*)(r + XS_LD)    = cvt4(xr1);
                    *(f16x4*)(r + 2*XS_LD)  = cvt4(xr2);
                    *(f16x4*)(r + 3*XS_LD)  = cvt4(xr3);
                }
                LGKM_BARRIER();
                {   // slice 1: stage rows sg*8+4..7
                    f16* r = &xs16[sg * 8 + 4][lane * 4];
                    *(f16x4*)(r)            = cvt4(xr4);
                    *(f16x4*)(r + XS_LD)    = cvt4(xr5);
                    *(f16x4*)(r + 2*XS_LD)  = cvt4(xr6);
                    *(f16x4*)(r + 3*XS_LD)  = cvt4(xr7);
                }
                LGKM_BARRIER();
                // slices 2-9: one kt each. A-rows = timesteps; bias seeded in C.
                f32x4 A0 = {bc0,bc0,bc0,bc0}, A1 = {bc1,bc1,bc1,bc1};
                f32x4 A2 = {bc2,bc2,bc2,bc2}, A3 = {bc3,bc3,bc3,bc3};
                f32x4 B0 = A0, B1 = A1, B2 = A2, B3 = A3;
                #pragma unroll
                for (int kt = 0; kt < 8; ++kt) {
                    f16x8 u0 = *(const f16x8*)&xs16[l15     ][kt * 32 + koff];
                    f16x8 u1 = *(const f16x8*)&xs16[l15 + 16][kt * 32 + koff];
                    A0 = MFMA16(u0, wf[0][kt], A0);
                    A1 = MFMA16(u0, wf[1][kt], A1);
                    A2 = MFMA16(u0, wf[2][kt], A2);
                    A3 = MFMA16(u0, wf[3][kt], A3);
                    B0 = MFMA16(u1, wf[0][kt], B0);
                    B1 = MFMA16(u1, wf[1][kt], B1);
                    B2 = MFMA16(u1, wf[2][kt], B2);
                    B3 = MFMA16(u1, wf[3][kt], B3);
                    LGKM_BARRIER();
                }
                // slice 10: transpose accs -> xwc4 (row = timestep, 4 cols/line)
                {
                    const int pw = phase & 1;
                    #pragma unroll
                    for (int r = 0; r < 4; ++r) {
                        f32x4 v = {A0[r], A1[r], A2[r], A3[r]};
                        *(f32x4*)&xwc4[pw][cq][grp * 4 + r][0] = v;
                        f32x4 w = {B0[r], B1[r], B2[r], B3[r]};
                        *(f32x4*)&xwc4[pw][cq][16 + grp * 4 + r][0] = w;
                    }
                }
                LGKM_BARRIER();
                // slice 11: issue next chunk's global prefetch (in flight across scan)
                if (phase + 1 < NCHUNK) LOADX(phase + 1);
                LGKM_BARRIER();
                // slices 12-31: pace the scan
                for (int i = 12; i < TC; ++i) LGKM_BARRIER();
            } else {
                for (int i = 0; i < TC; ++i) LGKM_BARRIER();
            }
        }
    }

    // th_keep's col = wbase + grp*16 + l15 = wbase + lane -> coalesced store
    if (sw) out[(size_t)b * Hv + wbase + lane] = th_keep;
}

extern "C" void kernel_launch(void* const* d_in, const int* in_sizes, int n_in,
                              void* d_out, int out_size, void* d_ws, size_t ws_size,
                              hipStream_t stream) {
    const float* x    = (const float*)d_in[0];   // [B,T,H]
    const float* wx   = (const float*)d_in[1];   // [H,H]
    const float* wh   = (const float*)d_in[2];   // [H,H]
    const float* bias = (const float*)d_in[3];   // [1,H]
    float* out = (float*)d_out;                  // [B,1,H]

    hipLaunchKernelGGL(HiddenLayer_704374636647_kernel,
                       dim3(Bv), dim3(512), 0, stream,
                       x, wx, wh, bias, out);
}

// Round 6
// 911.707 us; speedup vs baseline: 1.1487x; 1.1487x over previous
//
#include <hip/hip_runtime.h>
#include <math.h>

// Vanilla RNN: h_t = tanh(h_{t-1} @ wh + x_t @ wx + b), out = h_T  [B,1,H]
// B=256, T=2048, H=256, fp32 in/out.
//
// Round 5: 4-wave blocks (256 threads), no wave specialization.
//  - Wall time = per-step serial latency (all 256 rows run concurrently on
//    256 CUs). Floor = 128 MFMA/CU/step x 4.85cy = 620cy pipe + tail.
//  - 1 wave/SIMD -> ~512 VGPR budget: BOTH wh frags (128 VGPR) and wx frags
//    (128 VGPR) stay resident. The chunk GEMM (64 MFMA/wave) runs serially
//    between chunks (~+47cy/step amortized); xwc single-buffered; no pacing
//    barriers; s_barrier converges 4 waves instead of 8.
//  - Scan: replicated-row MFMA recurrence (r3/r4, verified), k-split=2,
//    chains seeded with hoisted zero-C; xw added at combine via cndmask
//    select computed off-critical-path from the prefetched seed.
//  - ONE raw s_barrier/step (lgkmcnt(0) only; vmcnt NOT drained so global
//    x prefetch stays in flight across the scan).

typedef _Float16 f16;
typedef _Float16 f16x4 __attribute__((ext_vector_type(4)));
typedef _Float16 f16x8 __attribute__((ext_vector_type(8)));
typedef float    f32x4 __attribute__((ext_vector_type(4)));

#define Bv 256
#define Tv 2048
#define Hv 256
#define TC 32
#define NCHUNK (Tv/TC)
#define XS_LD 264          // f16 row stride (528B -> 2-way banks, free)
#define XW_TS (TC+1)       // ts-dim pad: cq stride 33*16B=528B -> 2-way banks

#define LGKM_BARRIER() do { \
    asm volatile("s_waitcnt lgkmcnt(0)" ::: "memory"); \
    __builtin_amdgcn_s_barrier(); \
} while (0)

#define MFMA16(a, b, c) __builtin_amdgcn_mfma_f32_16x16x32_f16((a), (b), (c), 0, 0, 0)

__device__ __forceinline__ f16x4 cvt4(float4 v) {
    f16x4 r; r[0] = (f16)v.x; r[1] = (f16)v.y; r[2] = (f16)v.z; r[3] = (f16)v.w;
    return r;
}

__global__ __launch_bounds__(256, 1)
void HiddenLayer_704374636647_kernel(const float* __restrict__ x,
                                     const float* __restrict__ wx,
                                     const float* __restrict__ wh,
                                     const float* __restrict__ bias,
                                     float* __restrict__ out)
{
    __shared__ __align__(16) f16   xs16[TC][XS_LD];     // 16.9 KB
    __shared__ __align__(16) float xwc4[64][XW_TS][4];  // 33.8 KB
    __shared__ __align__(16) f16   hbuf[2][Hv];         //  1.0 KB

    const int  tid   = threadIdx.x;       // 0..255
    const int  wave  = tid >> 6;          // 0..3
    const int  lane  = tid & 63;
    const int  b     = blockIdx.x;
    const int  wbase = wave * 64;         // 64-col slice owned by wave
    const int  l15   = lane & 15;
    const int  grp   = lane >> 4;         // 0..3
    const int  cq    = wave * 16 + l15;   // xwc4 column-quad index
    const int  koff  = grp * 8;           // A-frag k-offset

    const float* xb = x + (size_t)b * Tv * Hv;

    // ---- global x prefetch: 8 rows (wave + 4s) x 4 f32/lane
    float4 xr0, xr1, xr2, xr3, xr4, xr5, xr6, xr7;
#define LOADX(cc) do { const float* p_ = xb + ((size_t)(cc) * TC + wave) * Hv + lane * 4; \
    xr0 = *(const float4*)(p_);           xr1 = *(const float4*)(p_ +  4 * Hv); \
    xr2 = *(const float4*)(p_ +  8 * Hv); xr3 = *(const float4*)(p_ + 12 * Hv); \
    xr4 = *(const float4*)(p_ + 16 * Hv); xr5 = *(const float4*)(p_ + 20 * Hv); \
    xr6 = *(const float4*)(p_ + 24 * Hv); xr7 = *(const float4*)(p_ + 28 * Hv); } while (0)

    LOADX(0);

    // ---- weight B-frags: tile t covers col wbase + t*16 + l15; k = kt*32 + koff + e
    f16x8 wfh[4][8];   // wh (recurrence), 128 VGPR
    f16x8 wfx[4][8];   // wx (projection), 128 VGPR
    #pragma unroll
    for (int t = 0; t < 4; ++t) {
        #pragma unroll
        for (int kt = 0; kt < 8; ++kt) {
            const float* ph = wh + (size_t)(kt * 32 + koff) * Hv + wbase + t * 16 + l15;
            const float* pw = wx + (size_t)(kt * 32 + koff) * Hv + wbase + t * 16 + l15;
            f16x8 vh, vw;
            #pragma unroll
            for (int e = 0; e < 8; ++e) {
                vh[e] = (f16)ph[(size_t)e * Hv];
                vw[e] = (f16)pw[(size_t)e * Hv];
            }
            wfh[t][kt] = vh;
            wfx[t][kt] = vw;
        }
    }

    const float bc0 = bias[wbase + l15];
    const float bc1 = bias[wbase + 16 + l15];
    const float bc2 = bias[wbase + 32 + l15];
    const float bc3 = bias[wbase + 48 + l15];

    hbuf[0][tid] = (f16)0.0f;   // h_0 = 0 (256 threads cover 256)

    int   cur     = 0;
    float th_keep = 0.0f;

    #pragma unroll 1
    for (int c = 0; c < NCHUNK; ++c) {
        // ---- stage prefetched x (f32->f16): row wave+4s, cols lane*4..+3
        *(f16x4*)&xs16[wave     ][lane * 4] = cvt4(xr0);
        *(f16x4*)&xs16[wave +  4][lane * 4] = cvt4(xr1);
        *(f16x4*)&xs16[wave +  8][lane * 4] = cvt4(xr2);
        *(f16x4*)&xs16[wave + 12][lane * 4] = cvt4(xr3);
        *(f16x4*)&xs16[wave + 16][lane * 4] = cvt4(xr4);
        *(f16x4*)&xs16[wave + 20][lane * 4] = cvt4(xr5);
        *(f16x4*)&xs16[wave + 24][lane * 4] = cvt4(xr6);
        *(f16x4*)&xs16[wave + 28][lane * 4] = cvt4(xr7);

        if (c + 1 < NCHUNK) LOADX(c + 1);   // in flight across GEMM + scan

        LGKM_BARRIER();   // xs16 visible (and hbuf zeros / xwc4 free)

        // ---- chunk GEMM: xwc4 = xs16 @ wx + bias (per wave: its 64 cols)
        {
            f32x4 gA0 = {bc0,bc0,bc0,bc0}, gA1 = {bc1,bc1,bc1,bc1};
            f32x4 gA2 = {bc2,bc2,bc2,bc2}, gA3 = {bc3,bc3,bc3,bc3};
            f32x4 gB0 = gA0, gB1 = gA1, gB2 = gA2, gB3 = gA3;
            #pragma unroll
            for (int kt = 0; kt < 8; ++kt) {
                f16x8 u0 = *(const f16x8*)&xs16[l15     ][kt * 32 + koff];
                f16x8 u1 = *(const f16x8*)&xs16[l15 + 16][kt * 32 + koff];
                gA0 = MFMA16(u0, wfx[0][kt], gA0);
                gA1 = MFMA16(u0, wfx[1][kt], gA1);
                gA2 = MFMA16(u0, wfx[2][kt], gA2);
                gA3 = MFMA16(u0, wfx[3][kt], gA3);
                gB0 = MFMA16(u1, wfx[0][kt], gB0);
                gB1 = MFMA16(u1, wfx[1][kt], gB1);
                gB2 = MFMA16(u1, wfx[2][kt], gB2);
                gB3 = MFMA16(u1, wfx[3][kt], gB3);
            }
            // D: row(ts) = grp*4 + r, col = l15 -> write [cq][ts] as 4-col quad
            #pragma unroll
            for (int r = 0; r < 4; ++r) {
                f32x4 v = {gA0[r], gA1[r], gA2[r], gA3[r]};
                *(f32x4*)&xwc4[cq][grp * 4 + r][0] = v;
                f32x4 w = {gB0[r], gB1[r], gB2[r], gB3[r]};
                *(f32x4*)&xwc4[cq][16 + grp * 4 + r][0] = w;
            }
        }

        LGKM_BARRIER();   // xwc4 visible

        // ---- scan TC steps, 1 barrier each (double-buffered h)
        f32x4 xwn = *(const f32x4*)&xwc4[cq][0][0];
        for (int ts = 0; ts < TC; ++ts) {
            const f16* hp = &hbuf[cur][koff];
            // issue all h-frag reads first (broadcast, conflict-free)
            f16x8 ha0 = *(const f16x8*)(hp);
            f16x8 ha1 = *(const f16x8*)(hp + 32);
            f16x8 ha2 = *(const f16x8*)(hp + 64);
            f16x8 ha3 = *(const f16x8*)(hp + 96);
            f16x8 ha4 = *(const f16x8*)(hp + 128);
            f16x8 ha5 = *(const f16x8*)(hp + 160);
            f16x8 ha6 = *(const f16x8*)(hp + 192);
            f16x8 ha7 = *(const f16x8*)(hp + 224);

            // this step's xw select (off critical path), then prefetch next
            float x01   = (grp & 1) ? xwn[1] : xwn[0];
            float x23   = (grp & 1) ? xwn[3] : xwn[2];
            float xwsel = (grp & 2) ? x23 : x01;
            const int tsn = (ts + 1 < TC) ? ts + 1 : ts;
            xwn = *(const f32x4*)&xwc4[cq][tsn][0];

            // k-split=2: two independent 4-deep chains per tile, zero-seeded
            const f32x4 z = {0.f, 0.f, 0.f, 0.f};
            f32x4 a0A = MFMA16(ha0, wfh[0][0], z), a0B = MFMA16(ha4, wfh[0][4], z);
            f32x4 a1A = MFMA16(ha0, wfh[1][0], z), a1B = MFMA16(ha4, wfh[1][4], z);
            f32x4 a2A = MFMA16(ha0, wfh[2][0], z), a2B = MFMA16(ha4, wfh[2][4], z);
            f32x4 a3A = MFMA16(ha0, wfh[3][0], z), a3B = MFMA16(ha4, wfh[3][4], z);

            a0A = MFMA16(ha1, wfh[0][1], a0A);  a0B = MFMA16(ha5, wfh[0][5], a0B);
            a1A = MFMA16(ha1, wfh[1][1], a1A);  a1B = MFMA16(ha5, wfh[1][5], a1B);
            a2A = MFMA16(ha1, wfh[2][1], a2A);  a2B = MFMA16(ha5, wfh[2][5], a2B);
            a3A = MFMA16(ha1, wfh[3][1], a3A);  a3B = MFMA16(ha5, wfh[3][5], a3B);

            a0A = MFMA16(ha2, wfh[0][2], a0A);  a0B = MFMA16(ha6, wfh[0][6], a0B);
            a1A = MFMA16(ha2, wfh[1][2], a1A);  a1B = MFMA16(ha6, wfh[1][6], a1B);
            a2A = MFMA16(ha2, wfh[2][2], a2A);  a2B = MFMA16(ha6, wfh[2][6], a2B);
            a3A = MFMA16(ha2, wfh[3][2], a3A);  a3B = MFMA16(ha6, wfh[3][6], a3B);

            a0A = MFMA16(ha3, wfh[0][3], a0A);  a0B = MFMA16(ha7, wfh[0][7], a0B);
            a1A = MFMA16(ha3, wfh[1][3], a1A);  a1B = MFMA16(ha7, wfh[1][7], a1B);
            a2A = MFMA16(ha3, wfh[2][3], a2A);  a2B = MFMA16(ha7, wfh[2][7], a2B);
            a3A = MFMA16(ha3, wfh[3][3], a3A);  a3B = MFMA16(ha7, wfh[3][7], a3B);

            // this lane owns tile (grp): col = wbase + grp*16 + l15 = wbase+lane
            float sA01 = (grp & 1) ? a1A[0] : a0A[0];
            float sA23 = (grp & 1) ? a3A[0] : a2A[0];
            float sA   = (grp & 2) ? sA23 : sA01;
            float sB01 = (grp & 1) ? a1B[0] : a0B[0];
            float sB23 = (grp & 1) ? a3B[0] : a2B[0];
            float sB   = (grp & 2) ? sB23 : sB01;
            float s    = (sA + sB) + xwsel;

            float scv = fminf(fmaxf(s, -12.f), 12.f);
            float e   = __expf(2.f * scv);
            float th  = 1.f - __fdividef(2.f, e + 1.f);
            th_keep = th;
            hbuf[cur ^ 1][wbase + lane] = (f16)th;
            LGKM_BARRIER();
            cur ^= 1;
        }
    }

    // th_keep's col = wbase + lane -> coalesced store
    out[(size_t)b * Hv + wbase + lane] = th_keep;
}

extern "C" void kernel_launch(void* const* d_in, const int* in_sizes, int n_in,
                              void* d_out, int out_size, void* d_ws, size_t ws_size,
                              hipStream_t stream) {
    const float* x    = (const float*)d_in[0];   // [B,T,H]
    const float* wx   = (const float*)d_in[1];   // [H,H]
    const float* wh   = (const float*)d_in[2];   // [H,H]
    const float* bias = (const float*)d_in[3];   // [1,H]
    float* out = (float*)d_out;                  // [B,1,H]

    hipLaunchKernelGGL(HiddenLayer_704374636647_kernel,
                       dim3(Bv), dim3(256), 0, stream,
                       x, wx, wh, bias, out);
}